// Round 14
// baseline (163.678 us; speedup 1.0000x reference)
//
#include <hip/hip_runtime.h>
#include <math.h>

#define NS 7
#define NK 6
#define TW 294   // torsion row width = NS*NS*NK
#define TPW 16   // triplets per wave
#define TPB 64   // triplets per block (4 waves)

typedef float f4 __attribute__((ext_vector_type(4)));

struct ConstTables {
    float zc[42];   // Bessel zeros z_{l,i}
    float nc[42];   // sqrt(2)/|j_{l+1}(z)|
    float Kc[49];   // real-SH normalization, flat f = l*l+l+m
};

__launch_bounds__(256, 6)
__global__ void fused_kernel(const float* __restrict__ dist,
                             const float* __restrict__ angle,
                             const float* __restrict__ torsion,
                             const float* __restrict__ freq,
                             const int* __restrict__ idx_kj,
                             float* __restrict__ outD,
                             float* __restrict__ outA,
                             float* __restrict__ outT,
                             int E, int T, int NBD,
                             ConstTables ct) {
    // smem: 4 wave-slices x 1488 floats (rbf[16][44] @0, cbf[16][49] @704);
    // dist path reuses smem[0..1535]
    __shared__ __align__(16) float smem[5952];
    const int tid = threadIdx.x;

    if (blockIdx.x < NBD) {
        // ================= dist-embedding path (first in grid) =================
        const int e0 = blockIdx.x * 256;
        int e = e0 + tid;
        int ec = e < E ? e : E - 1;
        float x = dist[ec] * 0.2f;
        float inv = 1.0f / x;
        float x2 = x * x;
        float xp0 = x2 * x2 * x;  // x^5
        float env = inv - 28.0f * xp0 + 48.0f * xp0 * x - 21.0f * xp0 * x2;
        float v[NK];
        #pragma unroll
        for (int i = 0; i < NK; ++i) v[i] = env * __sinf(freq[i] * x);
        if (e0 + 256 <= E) {
            #pragma unroll
            for (int i = 0; i < NK; ++i) smem[tid * 6 + i] = v[i];
            __syncthreads();
            const f4* b4 = (const f4*)smem;
            f4* o4 = (f4*)(outD + (size_t)e0 * 6);
            __builtin_nontemporal_store(b4[tid], o4 + tid);
            if (tid < 128) __builtin_nontemporal_store(b4[256 + tid], o4 + 256 + tid);
        } else if (e < E) {
            #pragma unroll
            for (int i = 0; i < NK; ++i) outD[(size_t)e * 6 + i] = v[i];
        }
        return;
    }

    // ================= triplet path: barrier-free, wave-independent =================
    const int w = tid >> 6, lane = tid & 63;
    float* __restrict__ rbf_s = smem + w * 1488;        // [16][44]
    float* __restrict__ cbf_s = smem + w * 1488 + 704;  // [16][49]
    const int t0w = (blockIdx.x - NBD) * TPB + w * TPW;

    // ---- phase 1 (within-wave)
    if (lane < TPW) {
        // cbf[49] for triplet slot `lane`, m-major (3-deep P chain)
        int t = t0w + lane;
        int tc = t < T ? t : T - 1;
        float ang = angle[tc];
        float phi = torsion[tc];

        float st = __sinf(ang), ct_ = __cosf(ang);
        float sp = __sinf(phi), cp = __cosf(phi);
        float sm[NS], cm[NS];
        sm[1] = sp; cm[1] = cp;
        #pragma unroll
        for (int m = 2; m < NS; ++m) {
            sm[m] = sm[m - 1] * cp + cm[m - 1] * sp;
            cm[m] = cm[m - 1] * cp - sm[m - 1] * sp;
        }

        float* cb = cbf_s + lane * 49;
        float pmm = 1.0f;  // P[m][m]
        #pragma unroll
        for (int m = 0; m < NS; ++m) {
            if (m > 0) pmm = (float)(1 - 2 * m) * pmm * st;
            {
                int f = m * m + m;
                if (m == 0) cb[f] = ct.Kc[f];
                else {
                    cb[f + m] = ct.Kc[f + m] * cm[m] * pmm;
                    cb[f - m] = ct.Kc[f - m] * sm[m] * pmm;
                }
            }
            if (m < NS - 1) {
                float plm1 = pmm;
                float pl = (float)(2 * m + 1) * ct_ * pmm;  // P[m+1][m]
                {
                    int l = m + 1, f = l * l + l;
                    if (m == 0) cb[f] = ct.Kc[f] * pl;
                    else {
                        cb[f + m] = ct.Kc[f + m] * cm[m] * pl;
                        cb[f - m] = ct.Kc[f - m] * sm[m] * pl;
                    }
                }
                #pragma unroll
                for (int l = m + 2; l < NS; ++l) {
                    float pn = ((float)(2 * l - 1) * ct_ * pl -
                                (float)(l + m - 1) * plm1) / (float)(l - m);
                    plm1 = pl; pl = pn;
                    int f = l * l + l;
                    if (m == 0) cb[f] = ct.Kc[f] * pl;
                    else {
                        cb[f + m] = ct.Kc[f + m] * cm[m] * pl;
                        cb[f - m] = ct.Kc[f - m] * sm[m] * pl;
                    }
                }
            }
        }
    } else {
        // rbf: lanes 16..63; each handles (s, p) for rows s and s+8; 7 evals each row
        int ww = lane - 16;
        int s = ww / 6, p = ww - 6 * s;
        int jlo = p * 7;
        #pragma unroll
        for (int half = 0; half < 2; ++half) {
            int srow = s + half * 8;
            int t = t0w + srow;
            int tc = t < T ? t : T - 1;
            int idx = idx_kj[tc];
            float x = dist[idx] * 0.2f;
            for (int jj = jlo; jj < jlo + 7; ++jj) {
                int l = jj / 6;
                float arg = ct.zc[jj] * x;
                float s1 = __sinf(arg), c1 = __cosf(arg);
                float inv = 1.0f / arg;
                float j0 = s1 * inv;
                float val = j0;
                if (l >= 1) {
                    float jm = j0;
                    float jcur = (s1 * inv - c1) * inv;
                    for (int ll = 2; ll <= l; ++ll) {
                        float tmp = (float)(2 * ll - 1) * inv * jcur - jm;
                        jm = jcur;
                        jcur = tmp;
                    }
                    val = jcur;
                }
                rbf_s[srow * 44 + jj] = ct.nc[jj] * val;
            }
        }
    }
    // within-wave LDS handoff: drain this wave's ds_writes; no block barrier.
    asm volatile("s_waitcnt lgkmcnt(0)" ::: "memory");
    __builtin_amdgcn_sched_barrier(0);

    int nvalid = T - t0w; if (nvalid > TPW) nvalid = TPW;

    if (nvalid == TPW) {
        // ---- phase 2: register products -> flat nontemporal dwordx4 stores.
        // Wave tile = 16 rows x 294 = 1176 f4 chunks; + 16 x 42 = 168 f4 chunks (angle).
        // Even col-pair shares a = c/42 and q = a*7 + (c%42)/6 (q never splits a pair).
        f4* __restrict__ gT = (f4*)(outT + (size_t)t0w * TW);
        unsigned row = (unsigned)(4 * lane) / 294u;
        unsigned c   = (unsigned)(4 * lane) - row * 294u;
        #pragma unroll
        for (int it = 0; it < 19; ++it) {
            if (it < 18 || lane < 24) {
                unsigned row1 = row, c1 = c + 2;
                if (c1 >= 294u) { c1 -= 294u; row1 += 1; }
                unsigned a0 = c / 42u,  r0 = c - a0 * 42u,  q0 = a0 * 7u + r0 / 6u;
                unsigned a1 = c1 / 42u, r1 = c1 - a1 * 42u, q1 = a1 * 7u + r1 / 6u;
                float qv0 = cbf_s[row * 49 + q0];
                float2 rv0 = *(const float2*)&rbf_s[row * 44 + r0];
                float qv1 = cbf_s[row1 * 49 + q1];
                float2 rv1 = *(const float2*)&rbf_s[row1 * 44 + r1];
                f4 val = { qv0 * rv0.x, qv0 * rv0.y, qv1 * rv1.x, qv1 * rv1.y };
                __builtin_nontemporal_store(val, gT + it * 64 + lane);
            }
            c += 256u;                      // +64 chunks = +256 floats
            if (c >= 294u) { c -= 294u; row += 1u; }
        }
        f4* __restrict__ gA = (f4*)(outA + (size_t)t0w * 42);
        #pragma unroll
        for (int it = 0; it < 3; ++it) {
            if (it < 2 || lane < 40) {
                unsigned flat = (unsigned)(4 * (it * 64 + lane));
                unsigned arow = flat / 42u, ac = flat - arow * 42u;
                unsigned arow1 = arow, ac1 = ac + 2;
                if (ac1 >= 42u) { ac1 -= 42u; arow1 += 1; }
                unsigned l0 = ac / 6u,  qa0 = l0 * l0 + l0;
                unsigned l1 = ac1 / 6u, qa1 = l1 * l1 + l1;
                float qv0 = cbf_s[arow * 49 + qa0];
                float2 rv0 = *(const float2*)&rbf_s[arow * 44 + ac];
                float qv1 = cbf_s[arow1 * 49 + qa1];
                float2 rv1 = *(const float2*)&rbf_s[arow1 * 44 + ac1];
                f4 val = { qv0 * rv0.x, qv0 * rv0.y, qv1 * rv1.x, qv1 * rv1.y };
                __builtin_nontemporal_store(val, gA + it * 64 + lane);
            }
        }
    } else {
        // partial tail (not hit when T % TPW == 0) — safe scalar path
        for (int g = lane; g < nvalid * TW; g += 64) {
            int row = g / TW, cc = g - row * TW;
            int a = cc / 42, r = cc - a * 42;
            outT[(size_t)t0w * TW + g] = cbf_s[row * 49 + a * 7 + r / 6] * rbf_s[row * 44 + r];
        }
        for (int g = lane; g < nvalid * 42; g += 64) {
            int row = g / 42, r = g - row * 42;
            int l = r / 6;
            outA[(size_t)t0w * 42 + g] = cbf_s[row * 49 + l * l + l] * rbf_s[row * 44 + r];
        }
    }
}

// ---- host-side double-precision table computation (pure CPU math; graph-safe) ----
static double jl_host(double x, int n) {
    double j0 = sin(x) / x;
    if (n == 0) return j0;
    double jm = j0, j = sin(x) / (x * x) - cos(x) / x;
    for (int l = 2; l <= n; ++l) {
        double t = (2.0 * l - 1.0) / x * j - jm;
        jm = j;
        j = t;
    }
    return j;
}

static void compute_tables(ConstTables* ct) {
    const double PI = 3.14159265358979323846;
    double zeros[NS][12];
    const int total = NK + NS - 1;  // 12
    for (int i = 0; i < total; ++i) zeros[0][i] = (i + 1) * PI;
    for (int l = 1; l < NS; ++l) {
        for (int i = 0; i < total - l; ++i) {
            double a = zeros[l - 1][i], b = zeros[l - 1][i + 1];
            double fa = jl_host(a, l);
            for (int it = 0; it < 100; ++it) {
                double m = 0.5 * (a + b);
                double fm = jl_host(m, l);
                if (fa * fm <= 0.0) b = m;
                else { a = m; fa = fm; }
            }
            zeros[l][i] = 0.5 * (a + b);
        }
    }
    for (int l = 0; l < NS; ++l) {
        for (int i = 0; i < NK; ++i) {
            double z = zeros[l][i];
            double jn1 = jl_host(z, l + 1);
            ct->zc[l * 6 + i] = (float)z;
            ct->nc[l * 6 + i] = (float)(1.0 / sqrt(0.5 * jn1 * jn1));
        }
    }
    double fact[13];
    fact[0] = 1.0;
    for (int i = 1; i < 13; ++i) fact[i] = fact[i - 1] * (double)i;
    ct->Kc[0] = (float)(0.5 / sqrt(PI));
    for (int l = 1; l < NS; ++l) {
        for (int m = -l; m <= l; ++m) {
            int am = m < 0 ? -m : m;
            double K = sqrt((2.0 * l + 1.0) / (4.0 * PI) * fact[l - am] / fact[l + am]);
            if (m != 0) K *= sqrt(2.0);
            ct->Kc[l * l + m + l] = (float)K;
        }
    }
}

extern "C" void kernel_launch(void* const* d_in, const int* in_sizes, int n_in,
                              void* d_out, int out_size, void* d_ws, size_t ws_size,
                              hipStream_t stream) {
    const float* dist    = (const float*)d_in[0];
    const float* angle   = (const float*)d_in[1];
    const float* torsion = (const float*)d_in[2];
    const float* freq    = (const float*)d_in[3];
    const int*   idx_kj  = (const int*)d_in[4];
    const int E = in_sizes[0];
    const int T = in_sizes[1];
    float* out = (float*)d_out;
    float* outA = out + (size_t)E * NK;
    float* outT = outA + (size_t)T * 42;

    ConstTables ct;
    compute_tables(&ct);

    const int NBT = (T + TPB - 1) / TPB;
    const int NBD = (E + 255) / 256;
    fused_kernel<<<NBD + NBT, 256, 0, stream>>>(dist, angle, torsion, freq, idx_kj,
                                                out, outA, outT, E, T, NBD, ct);
}

// Round 15
// 154.081 us; speedup vs baseline: 1.0623x; 1.0623x over previous
//
#include <hip/hip_runtime.h>
#include <math.h>

#define NS 7
#define NK 6
#define TW 294   // torsion row width = NS*NS*NK
#define TPW 8    // triplets per wave
#define TPB 32   // triplets per block (4 waves)

typedef float f4 __attribute__((ext_vector_type(4)));

struct ConstTables {
    float zc[42];   // Bessel zeros z_{l,i}
    float nc[42];   // sqrt(2)/|j_{l+1}(z)|
    float Kc[49];   // real-SH normalization, flat f = l*l+l+m
};

__launch_bounds__(256, 8)
__global__ void fused_kernel(const float* __restrict__ dist,
                             const float* __restrict__ angle,
                             const float* __restrict__ torsion,
                             const float* __restrict__ freq,
                             const int* __restrict__ idx_kj,
                             float* __restrict__ outD,
                             float* __restrict__ outA,
                             float* __restrict__ outT,
                             int E, int T, int NBD,
                             ConstTables ct) {
    // smem union: triplet path 4 wave-slices x 744 floats (rbf[8][44] + cbf[8][49]);
    // dist path buf[1536]
    __shared__ __align__(16) float smem[2976];
    const int tid = threadIdx.x;

    if (blockIdx.x < NBD) {
        // ================= dist-embedding path (first in grid) =================
        const int e0 = blockIdx.x * 256;
        int e = e0 + tid;
        int ec = e < E ? e : E - 1;
        float x = dist[ec] * 0.2f;
        float inv = 1.0f / x;
        float x2 = x * x;
        float xp0 = x2 * x2 * x;  // x^5
        float env = inv - 28.0f * xp0 + 48.0f * xp0 * x - 21.0f * xp0 * x2;
        float v[NK];
        #pragma unroll
        for (int i = 0; i < NK; ++i) v[i] = env * __sinf(freq[i] * x);
        if (e0 + 256 <= E) {
            #pragma unroll
            for (int i = 0; i < NK; ++i) smem[tid * 6 + i] = v[i];
            __syncthreads();
            const f4* b4 = (const f4*)smem;
            f4* o4 = (f4*)(outD + (size_t)e0 * 6);
            __builtin_nontemporal_store(b4[tid], o4 + tid);
            if (tid < 128) __builtin_nontemporal_store(b4[256 + tid], o4 + 256 + tid);
        } else if (e < E) {
            #pragma unroll
            for (int i = 0; i < NK; ++i) outD[(size_t)e * 6 + i] = v[i];
        }
        return;
    }

    // ================= triplet path: barrier-free, wave-independent =================
    const int w = tid >> 6, lane = tid & 63;
    float* __restrict__ rbf_s = smem + w * 744;        // [8][44]
    float* __restrict__ cbf_s = smem + w * 744 + 352;  // [8][49]
    const int t0w = (blockIdx.x - NBD) * TPB + w * TPW;

    // ---- phase 1 (within-wave)
    if (lane < TPW) {
        // cbf[49] for triplet slot `lane`, m-major (3-deep P chain)
        int t = t0w + lane;
        int tc = t < T ? t : T - 1;
        float ang = angle[tc];
        float phi = torsion[tc];

        float st = __sinf(ang), ct_ = __cosf(ang);
        float sp = __sinf(phi), cp = __cosf(phi);
        float sm[NS], cm[NS];
        sm[1] = sp; cm[1] = cp;
        #pragma unroll
        for (int m = 2; m < NS; ++m) {
            sm[m] = sm[m - 1] * cp + cm[m - 1] * sp;
            cm[m] = cm[m - 1] * cp - sm[m - 1] * sp;
        }

        float* cb = cbf_s + lane * 49;
        float pmm = 1.0f;  // P[m][m]
        #pragma unroll
        for (int m = 0; m < NS; ++m) {
            if (m > 0) pmm = (float)(1 - 2 * m) * pmm * st;
            {
                int f = m * m + m;
                if (m == 0) cb[f] = ct.Kc[f];
                else {
                    cb[f + m] = ct.Kc[f + m] * cm[m] * pmm;
                    cb[f - m] = ct.Kc[f - m] * sm[m] * pmm;
                }
            }
            if (m < NS - 1) {
                float plm1 = pmm;
                float pl = (float)(2 * m + 1) * ct_ * pmm;  // P[m+1][m]
                {
                    int l = m + 1, f = l * l + l;
                    if (m == 0) cb[f] = ct.Kc[f] * pl;
                    else {
                        cb[f + m] = ct.Kc[f + m] * cm[m] * pl;
                        cb[f - m] = ct.Kc[f - m] * sm[m] * pl;
                    }
                }
                #pragma unroll
                for (int l = m + 2; l < NS; ++l) {
                    float pn = ((float)(2 * l - 1) * ct_ * pl -
                                (float)(l + m - 1) * plm1) / (float)(l - m);
                    plm1 = pl; pl = pn;
                    int f = l * l + l;
                    if (m == 0) cb[f] = ct.Kc[f] * pl;
                    else {
                        cb[f + m] = ct.Kc[f + m] * cm[m] * pl;
                        cb[f - m] = ct.Kc[f - m] * sm[m] * pl;
                    }
                }
            }
        }
    } else if (lane >= 16) {
        // rbf: 6 lanes per triplet, 7 Bessel evals each (fast HW trig)
        int ww = lane - 16;
        int s = ww / 6, p = ww - 6 * s;
        int t = t0w + s;
        int tc = t < T ? t : T - 1;
        int idx = idx_kj[tc];
        float x = dist[idx] * 0.2f;
        int jlo = p * 7;
        for (int jj = jlo; jj < jlo + 7; ++jj) {
            int l = jj / 6;
            float arg = ct.zc[jj] * x;
            float s1 = __sinf(arg), c1 = __cosf(arg);
            float inv = 1.0f / arg;
            float j0 = s1 * inv;
            float val = j0;
            if (l >= 1) {
                float jm = j0;
                float jcur = (s1 * inv - c1) * inv;
                for (int ll = 2; ll <= l; ++ll) {
                    float tmp = (float)(2 * ll - 1) * inv * jcur - jm;
                    jm = jcur;
                    jcur = tmp;
                }
                val = jcur;
            }
            rbf_s[s * 44 + jj] = ct.nc[jj] * val;
        }
    }
    // within-wave LDS handoff: drain this wave's ds_writes; no block barrier.
    asm volatile("s_waitcnt lgkmcnt(0)" ::: "memory");
    __builtin_amdgcn_sched_barrier(0);

    int nvalid = T - t0w; if (nvalid > TPW) nvalid = TPW;

    if (nvalid == TPW) {
        // ---- phase 2: register products -> flat nontemporal dwordx4 stores.
        // Wave tile = 8 rows x 294 = 588 f4 chunks; +8 x 42 = 84 f4 chunks (angle).
        // Even col-pair shares a = c/42 and q = a*7 + (c%42)/6 (q never splits a pair).
        f4* __restrict__ gT = (f4*)(outT + (size_t)t0w * TW);
        unsigned row = (unsigned)(4 * lane) / 294u;
        unsigned c   = (unsigned)(4 * lane) - row * 294u;
        #pragma unroll
        for (int it = 0; it < 10; ++it) {
            if (it < 9 || lane < 12) {
                unsigned row1 = row, c1 = c + 2;
                if (c1 >= 294u) { c1 -= 294u; row1 += 1; }
                unsigned a0 = c / 42u,  r0 = c - a0 * 42u,  q0 = a0 * 7u + r0 / 6u;
                unsigned a1 = c1 / 42u, r1 = c1 - a1 * 42u, q1 = a1 * 7u + r1 / 6u;
                float qv0 = cbf_s[row * 49 + q0];
                float2 rv0 = *(const float2*)&rbf_s[row * 44 + r0];
                float qv1 = cbf_s[row1 * 49 + q1];
                float2 rv1 = *(const float2*)&rbf_s[row1 * 44 + r1];
                f4 val = { qv0 * rv0.x, qv0 * rv0.y, qv1 * rv1.x, qv1 * rv1.y };
                __builtin_nontemporal_store(val, gT + it * 64 + lane);
            }
            c += 256u;                      // +64 chunks = +256 floats
            if (c >= 294u) { c -= 294u; row += 1u; }
        }
        f4* __restrict__ gA = (f4*)(outA + (size_t)t0w * 42);
        #pragma unroll
        for (int it = 0; it < 2; ++it) {
            if (it < 1 || lane < 20) {
                unsigned flat = (unsigned)(4 * (it * 64 + lane));
                unsigned arow = flat / 42u, ac = flat - arow * 42u;
                unsigned arow1 = arow, ac1 = ac + 2;
                if (ac1 >= 42u) { ac1 -= 42u; arow1 += 1; }
                unsigned l0 = ac / 6u,  qa0 = l0 * l0 + l0;
                unsigned l1 = ac1 / 6u, qa1 = l1 * l1 + l1;
                float qv0 = cbf_s[arow * 49 + qa0];
                float2 rv0 = *(const float2*)&rbf_s[arow * 44 + ac];
                float qv1 = cbf_s[arow1 * 49 + qa1];
                float2 rv1 = *(const float2*)&rbf_s[arow1 * 44 + ac1];
                f4 val = { qv0 * rv0.x, qv0 * rv0.y, qv1 * rv1.x, qv1 * rv1.y };
                __builtin_nontemporal_store(val, gA + it * 64 + lane);
            }
        }
    } else {
        // partial tail (not hit when T % 8 == 0) — safe scalar path
        for (int g = lane; g < nvalid * TW; g += 64) {
            int row = g / TW, cc = g - row * TW;
            int a = cc / 42, r = cc - a * 42;
            outT[(size_t)t0w * TW + g] = cbf_s[row * 49 + a * 7 + r / 6] * rbf_s[row * 44 + r];
        }
        for (int g = lane; g < nvalid * 42; g += 64) {
            int row = g / 42, r = g - row * 42;
            int l = r / 6;
            outA[(size_t)t0w * 42 + g] = cbf_s[row * 49 + l * l + l] * rbf_s[row * 44 + r];
        }
    }
}

// ---- host-side double-precision table computation (pure CPU math; graph-safe) ----
static double jl_host(double x, int n) {
    double j0 = sin(x) / x;
    if (n == 0) return j0;
    double jm = j0, j = sin(x) / (x * x) - cos(x) / x;
    for (int l = 2; l <= n; ++l) {
        double t = (2.0 * l - 1.0) / x * j - jm;
        jm = j;
        j = t;
    }
    return j;
}

static void compute_tables(ConstTables* ct) {
    const double PI = 3.14159265358979323846;
    double zeros[NS][12];
    const int total = NK + NS - 1;  // 12
    for (int i = 0; i < total; ++i) zeros[0][i] = (i + 1) * PI;
    for (int l = 1; l < NS; ++l) {
        for (int i = 0; i < total - l; ++i) {
            double a = zeros[l - 1][i], b = zeros[l - 1][i + 1];
            double fa = jl_host(a, l);
            for (int it = 0; it < 100; ++it) {
                double m = 0.5 * (a + b);
                double fm = jl_host(m, l);
                if (fa * fm <= 0.0) b = m;
                else { a = m; fa = fm; }
            }
            zeros[l][i] = 0.5 * (a + b);
        }
    }
    for (int l = 0; l < NS; ++l) {
        for (int i = 0; i < NK; ++i) {
            double z = zeros[l][i];
            double jn1 = jl_host(z, l + 1);
            ct->zc[l * 6 + i] = (float)z;
            ct->nc[l * 6 + i] = (float)(1.0 / sqrt(0.5 * jn1 * jn1));
        }
    }
    double fact[13];
    fact[0] = 1.0;
    for (int i = 1; i < 13; ++i) fact[i] = fact[i - 1] * (double)i;
    ct->Kc[0] = (float)(0.5 / sqrt(PI));
    for (int l = 1; l < NS; ++l) {
        for (int m = -l; m <= l; ++m) {
            int am = m < 0 ? -m : m;
            double K = sqrt((2.0 * l + 1.0) / (4.0 * PI) * fact[l - am] / fact[l + am]);
            if (m != 0) K *= sqrt(2.0);
            ct->Kc[l * l + m + l] = (float)K;
        }
    }
}

extern "C" void kernel_launch(void* const* d_in, const int* in_sizes, int n_in,
                              void* d_out, int out_size, void* d_ws, size_t ws_size,
                              hipStream_t stream) {
    const float* dist    = (const float*)d_in[0];
    const float* angle   = (const float*)d_in[1];
    const float* torsion = (const float*)d_in[2];
    const float* freq    = (const float*)d_in[3];
    const int*   idx_kj  = (const int*)d_in[4];
    const int E = in_sizes[0];
    const int T = in_sizes[1];
    float* out = (float*)d_out;
    float* outA = out + (size_t)E * NK;
    float* outT = outA + (size_t)T * 42;

    ConstTables ct;
    compute_tables(&ct);

    const int NBT = (T + TPB - 1) / TPB;
    const int NBD = (E + 255) / 256;
    fused_kernel<<<NBD + NBT, 256, 0, stream>>>(dist, angle, torsion, freq, idx_kj,
                                                out, outA, outT, E, T, NBD, ct);
}